// Round 7
// baseline (522.189 us; speedup 1.0000x reference)
//
#include <hip/hip_runtime.h>
#include <math.h>

#define MD 1024
#define NH 16
#define HD 64
#define BATCH 4
#define SEQ 2048

typedef __attribute__((ext_vector_type(8))) short short8;
typedef __attribute__((ext_vector_type(4))) short short4v;
typedef __attribute__((ext_vector_type(4))) float f32x4;
typedef __attribute__((ext_vector_type(2))) unsigned int uint2v;

#define GLOAD16(gp, lp) __builtin_amdgcn_global_load_lds( \
    (const __attribute__((address_space(1))) void*)(gp),  \
    (__attribute__((address_space(3))) void*)(lp), 16, 0, 0)

__device__ inline unsigned short f2b(float f) {
    unsigned u = __builtin_bit_cast(unsigned, f);
    unsigned r = (u + 0x7fffu + ((u >> 16) & 1u)) >> 16;
    return (unsigned short)r;
}
__device__ inline float b2f(unsigned short s) {
    return __builtin_bit_cast(float, ((unsigned)s) << 16);
}

// ---------------------------------------------------------------------------
// Fused prep: y<3 -> fp32->bf16 convert of q/k/v activations;
//             y==3 -> W[K][N] fp32 -> WT[N][K] bf16 for all 4 weights.
// Grid (4096, 4).  [proven R4/R5]
// ---------------------------------------------------------------------------
__global__ __launch_bounds__(256)
void prep_kernel(const float* __restrict__ x0, const float* __restrict__ x1,
                 const float* __restrict__ x2, unsigned short* __restrict__ y0,
                 unsigned short* __restrict__ y1, unsigned short* __restrict__ y2,
                 int n,
                 const float* __restrict__ W0, const float* __restrict__ W1,
                 const float* __restrict__ W2, const float* __restrict__ W3,
                 unsigned short* __restrict__ T0, unsigned short* __restrict__ T1,
                 unsigned short* __restrict__ T2, unsigned short* __restrict__ T3)
{
    __shared__ __attribute__((aligned(16))) float T[64][68];
    const int tid = threadIdx.x;
    if (blockIdx.y < 3) {
        const float* x = (blockIdx.y == 0) ? x0 : (blockIdx.y == 1) ? x1 : x2;
        unsigned short* y = (blockIdx.y == 0) ? y0 : (blockIdx.y == 1) ? y1 : y2;
        int i = (blockIdx.x * 256 + tid) * 8;
        if (i >= n) return;
        f32x4 a = *(const f32x4*)(x + i);
        f32x4 b = *(const f32x4*)(x + i + 4);
        short8 o;
        o[0] = (short)f2b(a[0]); o[1] = (short)f2b(a[1]);
        o[2] = (short)f2b(a[2]); o[3] = (short)f2b(a[3]);
        o[4] = (short)f2b(b[0]); o[5] = (short)f2b(b[1]);
        o[6] = (short)f2b(b[2]); o[7] = (short)f2b(b[3]);
        *(short8*)(y + i) = o;
        return;
    }
    const int bx = blockIdx.x;
    if (bx >= 1024) return;
    const int z = bx >> 8, t = bx & 255;
    const int nt = t & 15, kt = t >> 4;
    const float* W = (z == 0) ? W0 : (z == 1) ? W1 : (z == 2) ? W2 : W3;
    unsigned short* WT = (z == 0) ? T0 : (z == 1) ? T1 : (z == 2) ? T2 : T3;
    #pragma unroll
    for (int i = 0; i < 4; ++i) {
        int u = tid + i * 256;
        int row = u >> 4, c4 = u & 15;
        f32x4 v = *(const f32x4*)(W + (size_t)(kt * 64 + row) * MD + nt * 64 + c4 * 4);
        *(f32x4*)&T[row][c4 * 4] = v;
    }
    __syncthreads();
    #pragma unroll
    for (int i = 0; i < 2; ++i) {
        int u = tid + i * 256;
        int nn = u >> 3, c16 = u & 7;
        short8 o;
        #pragma unroll
        for (int j = 0; j < 8; ++j) o[j] = (short)f2b(T[c16 * 8 + j][nn]);
        *(short8*)(WT + (size_t)(nt * 64 + nn) * MD + kt * 64 + c16 * 8) = o;
    }
}

// ---------------------------------------------------------------------------
// GEMM core: 128x128 tile, BK=64, bf16 A/B via global_load_lds width-16,
// XCD-swizzled block id. [proven R3-R5]
// ---------------------------------------------------------------------------
__device__ __forceinline__
void gemm_core(const unsigned short* __restrict__ A,
               const unsigned short* __restrict__ Bt,
               short* As, short* Bs, f32x4 acc[4][4],
               int* obrow, int* obcol)
{
    const int tid = threadIdx.x;
    const int lane = tid & 63;
    const int wave = tid >> 6;
    const int wm = wave >> 1, wn = wave & 1;
    const int l15 = lane & 15, g = lane >> 4;

    const int nbx = gridDim.x;
    const int bid = blockIdx.y * nbx + blockIdx.x;
    const int cpx = (nbx * gridDim.y) >> 3;
    const int swz = (bid & 7) * cpx + (bid >> 3);
    const int brow = (swz / nbx) * 128;
    const int bcol = (swz % nbx) * 128;
    *obrow = brow; *obcol = bcol;

    #pragma unroll
    for (int m = 0; m < 4; ++m)
        #pragma unroll
        for (int n = 0; n < 4; ++n) acc[m][n] = (f32x4){0.f, 0.f, 0.f, 0.f};

    for (int k0 = 0; k0 < MD; k0 += 64) {
        __syncthreads();
        #pragma unroll
        for (int i = 0; i < 4; ++i) {
            const int U = (i * 4 + wave) * 64 + lane;
            const int row = U >> 3, c16 = U & 7;
            GLOAD16(A  + (size_t)(brow + row) * MD + k0 + c16 * 8, &As[U * 8]);
            GLOAD16(Bt + (size_t)(bcol + row) * MD + k0 + c16 * 8, &Bs[U * 8]);
        }
        __syncthreads();
        #pragma unroll
        for (int kk = 0; kk < 64; kk += 32) {
            short8 af[4], bf_[4];
            #pragma unroll
            for (int m = 0; m < 4; ++m)
                af[m] = *(const short8*)&As[(wm * 64 + m * 16 + l15) * 64 + kk + g * 8];
            #pragma unroll
            for (int n = 0; n < 4; ++n)
                bf_[n] = *(const short8*)&Bs[(wn * 64 + n * 16 + l15) * 64 + kk + g * 8];
            #pragma unroll
            for (int m = 0; m < 4; ++m)
                #pragma unroll
                for (int n = 0; n < 4; ++n)
                    acc[m][n] = __builtin_amdgcn_mfma_f32_16x16x32_bf16(af[m], bf_[n], acc[m][n], 0, 0, 0);
        }
    }
}

// Q/K/V projections in one launch; blockIdx.z selects.
// z=0: Q -> bf16 scaled by 0.125*log2(e).  z=1: K -> bf16.
// z=2: V -> transposed bf16 vt[bh*64+d][s].  [proven R5]
__global__ __launch_bounds__(256, 2)
void gemm_qkv(const unsigned short* __restrict__ A0, const unsigned short* __restrict__ A1,
              const unsigned short* __restrict__ A2,
              const unsigned short* __restrict__ B0, const unsigned short* __restrict__ B1,
              const unsigned short* __restrict__ B2,
              const float* __restrict__ b0, const float* __restrict__ b1,
              const float* __restrict__ b2,
              unsigned short* __restrict__ Cq, unsigned short* __restrict__ Ck,
              unsigned short* __restrict__ Cvt)
{
    __shared__ __attribute__((aligned(16))) short As[128 * 64];
    __shared__ __attribute__((aligned(16))) short Bs[128 * 64];
    const int z = blockIdx.z;
    const unsigned short* A  = (z == 0) ? A0 : (z == 1) ? A1 : A2;
    const unsigned short* Bt = (z == 0) ? B0 : (z == 1) ? B1 : B2;
    const float* bias        = (z == 0) ? b0 : (z == 1) ? b1 : b2;

    f32x4 acc[4][4];
    int brow, bcol;
    gemm_core(A, Bt, As, Bs, acc, &brow, &bcol);

    const int tid = threadIdx.x;
    const int lane = tid & 63;
    const int wave = tid >> 6;
    const int wm = wave >> 1, wn = wave & 1;
    const int l15 = lane & 15, g = lane >> 4;

    if (z == 2) {
        #pragma unroll
        for (int m = 0; m < 4; ++m) {
            #pragma unroll
            for (int n = 0; n < 4; ++n) {
                const int col = bcol + wn * 64 + n * 16 + l15;
                const int h = col >> 6, d = col & 63;
                const float bv_ = bias[col];
                const int row0 = brow + wm * 64 + m * 16 + 4 * g;
                const int bb = row0 >> 11, s = row0 & 2047;
                short4v pk;
                #pragma unroll
                for (int r = 0; r < 4; ++r) pk[r] = (short)f2b(acc[m][n][r] + bv_);
                *(short4v*)(Cvt + ((size_t)((bb << 4) + h) * 64 + d) * SEQ + s) = pk;
            }
        }
        return;
    }
    const float scale = (z == 0) ? (0.125f * 1.44269504088896f) : 1.0f;
    unsigned short* C = (z == 0) ? Cq : Ck;
    #pragma unroll
    for (int m = 0; m < 4; ++m) {
        #pragma unroll
        for (int n = 0; n < 4; ++n) {
            const int col = bcol + wn * 64 + n * 16 + l15;
            const float bcol_v = bias[col];
            #pragma unroll
            for (int r = 0; r < 4; ++r) {
                const size_t row = (size_t)(brow + wm * 64 + m * 16 + 4 * g + r);
                C[row * MD + col] = f2b((acc[m][n][r] + bcol_v) * scale);
            }
        }
    }
}

// O-projection: fp32 out + bias + residual. [proven R5]
__global__ __launch_bounds__(256, 2)
void gemm_o(const unsigned short* __restrict__ A, const unsigned short* __restrict__ Bt,
            const float* __restrict__ bias, const float* __restrict__ residual,
            float* __restrict__ Cf)
{
    __shared__ __attribute__((aligned(16))) short As[128 * 64];
    __shared__ __attribute__((aligned(16))) short Bs[128 * 64];
    f32x4 acc[4][4];
    int brow, bcol;
    gemm_core(A, Bt, As, Bs, acc, &brow, &bcol);

    const int tid = threadIdx.x;
    const int lane = tid & 63;
    const int wave = tid >> 6;
    const int wm = wave >> 1, wn = wave & 1;
    const int l15 = lane & 15, g = lane >> 4;
    #pragma unroll
    for (int m = 0; m < 4; ++m) {
        #pragma unroll
        for (int n = 0; n < 4; ++n) {
            const int col = bcol + wn * 64 + n * 16 + l15;
            const float bcol_v = bias[col];
            #pragma unroll
            for (int r = 0; r < 4; ++r) {
                const size_t row = (size_t)(brow + wm * 64 + m * 16 + 4 * g + r);
                Cf[row * MD + col] = acc[m][n][r] + bcol_v + residual[row * MD + col];
            }
        }
    }
}

// ---------------------------------------------------------------------------
// Flash attention, bf16 MFMA. QBLK=256 (64 q-rows/wave), KV tile 64.
// LDS 48KB -> 3 blocks/CU: full 32KB P (R5 swizzle) + SINGLE-buffered K/V
// (8KB each), two barriers/tile (R3-proven ordering: bar; LDS-write;
// prefetch-issue; bar; compute). bh-grouped XCD swizzle (all 8 q-tiles of a
// (b,h) on one XCD). exp2 softmax, defer-max, fmax-chain pmax, row-sums via
// mfma(P, ones). Grid (8, 64), 256 thr = 4 waves.
// ---------------------------------------------------------------------------
__global__ __launch_bounds__(256, 3)
void attn_mfma(const unsigned short* __restrict__ qp,
               const unsigned short* __restrict__ kp,
               const unsigned short* __restrict__ vt,
               unsigned short* __restrict__ ao)
{
    __shared__ __attribute__((aligned(16))) short Ps[256 * 64];   // 32KB
    __shared__ __attribute__((aligned(16))) short Ks[64 * 64];    // 8KB
    __shared__ __attribute__((aligned(16))) short Vts[64 * 64];   // 8KB

    const int tid = threadIdx.x;
    const int lane = tid & 63;
    const int wave = tid >> 6;
    const int l15 = lane & 15, g = lane >> 4;

    // bh-grouped XCD swizzle: lin%8 fixes XCD slot; all qt of a bh share it
    const int lin = blockIdx.y * gridDim.x + blockIdx.x;   // 0..511
    const int xi = lin & 7, j = lin >> 3;
    const int bh = xi + 8 * (j & 7);
    const int qt = j >> 3;

    const int b = bh >> 4, h = bh & 15;
    const size_t rowbase = (size_t)b * SEQ;
    const int q0 = qt * 256;
    const int wq = wave * 64;
    const int NT = SEQ / 64;

    // staging geometry
    const int r0 = tid >> 3, c16 = tid & 7;
    const int r1 = r0 + 32;
    const int lds0 = (r0 * 8 + (c16 ^ (r0 & 7))) * 8;
    const int lds1 = (r1 * 8 + (c16 ^ (r1 & 7))) * 8;
    const unsigned short* kbase = kp + (rowbase + r0) * MD + h * 64 + c16 * 8;
    const unsigned short* vbase = vt + ((size_t)bh * 64 + r0) * SEQ + c16 * 8;

    // ---- Q direct to registers (pre-scaled by Q-GEMM epilogue) ----
    short8 qreg[4][2];
    #pragma unroll
    for (int nf = 0; nf < 4; ++nf)
        #pragma unroll
        for (int ki = 0; ki < 2; ++ki)
            qreg[nf][ki] = *(const short8*)(qp + (rowbase + q0 + wq + nf * 16 + l15) * MD
                                               + h * 64 + ki * 32 + g * 8);

    // ---- prologue: load KV tile 0 into regs ----
    short8 kreg0 = *(const short8*)(kbase);
    short8 kreg1 = *(const short8*)(kbase + 32 * MD);
    short8 vreg0 = *(const short8*)(vbase);
    short8 vreg1 = *(const short8*)(vbase + 32 * SEQ);

    short8 ones;
    #pragma unroll
    for (int jj = 0; jj < 8; ++jj) ones[jj] = (short)0x3F80;

    float mrun[4] = {-INFINITY, -INFINITY, -INFINITY, -INFINITY};
    f32x4 lrun[4];
    f32x4 off[4][4];
    #pragma unroll
    for (int qf = 0; qf < 4; ++qf) {
        lrun[qf] = (f32x4){0.f, 0.f, 0.f, 0.f};
        #pragma unroll
        for (int df = 0; df < 4; ++df) off[qf][df] = (f32x4){0.f, 0.f, 0.f, 0.f};
    }

    for (int kt = 0; kt < NT; ++kt) {
        // barrier A: prior tile's Ks/Vts reads complete
        __syncthreads();
        *(short8*)&Ks[lds0]  = kreg0;
        *(short8*)&Ks[lds1]  = kreg1;
        *(short8*)&Vts[lds0] = vreg0;
        *(short8*)&Vts[lds1] = vreg1;
        // issue next-tile prefetch (in flight during compute)
        if (kt + 1 < NT) {
            const unsigned short* kb = kbase + (size_t)(kt + 1) * 64 * MD;
            const unsigned short* vb = vbase + (kt + 1) * 64;
            kreg0 = *(const short8*)(kb);
            kreg1 = *(const short8*)(kb + 32 * MD);
            vreg0 = *(const short8*)(vb);
            vreg1 = *(const short8*)(vb + 32 * SEQ);
        }
        // barrier B: Ks/Vts visible to all waves
        __syncthreads();

        // ---- S^T = K @ Q^T ----
        f32x4 sc[4][4];
        #pragma unroll
        for (int mf = 0; mf < 4; ++mf)
            #pragma unroll
            for (int nf = 0; nf < 4; ++nf) sc[mf][nf] = (f32x4){0.f, 0.f, 0.f, 0.f};
        __builtin_amdgcn_s_setprio(1);
        #pragma unroll
        for (int ki = 0; ki < 2; ++ki) {
            const int cu = ki * 4 + g;
            short8 af[4];
            #pragma unroll
            for (int mf = 0; mf < 4; ++mf) {
                int row = mf * 16 + l15;
                af[mf] = *(const short8*)&Ks[(row * 8 + (cu ^ (row & 7))) * 8];
            }
            #pragma unroll
            for (int mf = 0; mf < 4; ++mf)
                #pragma unroll
                for (int nf = 0; nf < 4; ++nf)
                    sc[mf][nf] = __builtin_amdgcn_mfma_f32_16x16x32_bf16(af[mf], qreg[nf][ki], sc[mf][nf], 0, 0, 0);
        }
        __builtin_amdgcn_s_setprio(0);

        // ---- online softmax (log2 domain), defer-max THR=8 ----
        float pmax[4];
        #pragma unroll
        for (int nf = 0; nf < 4; ++nf) {
            float pm = fmaxf(fmaxf(sc[0][nf][0], sc[0][nf][1]), sc[0][nf][2]);
            pm = fmaxf(fmaxf(pm, sc[0][nf][3]), sc[1][nf][0]);
            pm = fmaxf(fmaxf(pm, sc[1][nf][1]), sc[1][nf][2]);
            pm = fmaxf(fmaxf(pm, sc[1][nf][3]), sc[2][nf][0]);
            pm = fmaxf(fmaxf(pm, sc[2][nf][1]), sc[2][nf][2]);
            pm = fmaxf(fmaxf(pm, sc[2][nf][3]), sc[3][nf][0]);
            pm = fmaxf(fmaxf(pm, sc[3][nf][1]), sc[3][nf][2]);
            pm = fmaxf(pm, sc[3][nf][3]);
            pm = fmaxf(pm, __shfl_xor(pm, 16));
            pm = fmaxf(pm, __shfl_xor(pm, 32));
            pmax[nf] = pm;
        }
        const int defer = (pmax[0] <= mrun[0] + 8.0f) && (pmax[1] <= mrun[1] + 8.0f) &&
                          (pmax[2] <= mrun[2] + 8.0f) && (pmax[3] <= mrun[3] + 8.0f);
        if (!__all(defer)) {
            float corr[4];
            #pragma unroll
            for (int nf = 0; nf < 4; ++nf) {
                float mnew = fmaxf(mrun[nf], pmax[nf]);
                corr[nf] = __builtin_amdgcn_exp2f(mrun[nf] - mnew);
                mrun[nf] = mnew;
            }
            #pragma unroll
            for (int qf = 0; qf < 4; ++qf)
                #pragma unroll
                for (int r = 0; r < 4; ++r) {
                    float c = __shfl(corr[qf], 4 * g + r);
                    lrun[qf][r] *= c;
                    #pragma unroll
                    for (int df = 0; df < 4; ++df) off[qf][df][r] *= c;
                }
        }
        #pragma unroll
        for (int nf = 0; nf < 4; ++nf) {
            const float nm = mrun[nf];
            #pragma unroll
            for (int mf = 0; mf < 4; ++mf)
                #pragma unroll
                for (int r = 0; r < 4; ++r)
                    sc[mf][nf][r] = __builtin_amdgcn_exp2f(sc[mf][nf][r] - nm);
        }

        // ---- pack P -> bf16, wave-own rows of Ps (full 32KB, R5 swizzle) ----
        #pragma unroll
        for (int nf = 0; nf < 4; ++nf) {
            int row = wq + nf * 16 + l15;
            #pragma unroll
            for (int mf = 0; mf < 4; ++mf) {
                unsigned p01, p23;
                asm("v_cvt_pk_bf16_f32 %0, %1, %2" : "=v"(p01) : "v"(sc[mf][nf][0]), "v"(sc[mf][nf][1]));
                asm("v_cvt_pk_bf16_f32 %0, %1, %2" : "=v"(p23) : "v"(sc[mf][nf][2]), "v"(sc[mf][nf][3]));
                uint2v pk = {p01, p23};
                int su = (mf * 2 + (g >> 1)) ^ (row & 7);
                *(uint2v*)&Ps[row * 64 + su * 8 + (g & 1) * 4] = pk;
            }
        }

        // ---- PV + row-sum MFMA ----
        f32x4 ts[4];
        #pragma unroll
        for (int qf = 0; qf < 4; ++qf) ts[qf] = (f32x4){0.f, 0.f, 0.f, 0.f};
        __builtin_amdgcn_s_setprio(1);
        #pragma unroll
        for (int ki = 0; ki < 2; ++ki) {
            const int cu = ki * 4 + g;
            short8 pa[4], vb[4];
            #pragma unroll
            for (int qf = 0; qf < 4; ++qf) {
                int row = wq + qf * 16 + l15;
                pa[qf] = *(const short8*)&Ps[(row * 8 + (cu ^ (row & 7))) * 8];
            }
            #pragma unroll
            for (int df = 0; df < 4; ++df) {
                int d = df * 16 + l15;
                vb[df] = *(const short8*)&Vts[(d * 8 + (cu ^ (d & 7))) * 8];
            }
            #pragma unroll
            for (int qf = 0; qf < 4; ++qf)
                #pragma unroll
                for (int df = 0; df < 4; ++df)
                    off[qf][df] = __builtin_amdgcn_mfma_f32_16x16x32_bf16(pa[qf], vb[df], off[qf][df], 0, 0, 0);
            #pragma unroll
            for (int qf = 0; qf < 4; ++qf)
                ts[qf] = __builtin_amdgcn_mfma_f32_16x16x32_bf16(pa[qf], ones, ts[qf], 0, 0, 0);
        }
        __builtin_amdgcn_s_setprio(0);
        #pragma unroll
        for (int qf = 0; qf < 4; ++qf)
            #pragma unroll
            for (int r = 0; r < 4; ++r) lrun[qf][r] += ts[qf][r];
    }

    // ---- normalize + store bf16 ----
    #pragma unroll
    for (int qf = 0; qf < 4; ++qf) {
        #pragma unroll
        for (int r = 0; r < 4; ++r) {
            const float inv = 1.0f / lrun[qf][r];
            const size_t row = rowbase + q0 + wq + qf * 16 + 4 * g + r;
            #pragma unroll
            for (int df = 0; df < 4; ++df) {
                float val = off[qf][df][r] * inv;
                ao[row * MD + h * 64 + df * 16 + l15] = f2b(val);
            }
        }
    }
}

// ---------------------------------------------------------------------------
// In-place LayerNorm over last dim (1024). One block per row, 256 threads.
// ---------------------------------------------------------------------------
__global__ __launch_bounds__(256)
void ln_kernel(float* __restrict__ X, const float* __restrict__ gamma,
               const float* __restrict__ beta)
{
    const int row = blockIdx.x;
    const int tid = threadIdx.x;
    float* px = X + (size_t)row * MD;
    f32x4 x = ((const f32x4*)px)[tid];
    float s  = x[0] + x[1] + x[2] + x[3];
    float ss = fmaf(x[0], x[0], fmaf(x[1], x[1], fmaf(x[2], x[2], x[3] * x[3])));
    #pragma unroll
    for (int off = 1; off < 64; off <<= 1) {
        s  += __shfl_xor(s,  off);
        ss += __shfl_xor(ss, off);
    }
    __shared__ float red[8];
    const int wid = tid >> 6;
    if ((tid & 63) == 0) { red[wid] = s; red[wid + 4] = ss; }
    __syncthreads();
    s  = red[0] + red[1] + red[2] + red[3];
    ss = red[4] + red[5] + red[6] + red[7];
    const float mu   = s * (1.0f / MD);
    const float var  = ss * (1.0f / MD) - mu * mu;
    const float rstd = rsqrtf(var + 1e-5f);
    f32x4 gm = ((const f32x4*)gamma)[tid];
    f32x4 be = ((const f32x4*)beta)[tid];
    f32x4 r;
    r[0] = (x[0] - mu) * rstd * gm[0] + be[0];
    r[1] = (x[1] - mu) * rstd * gm[1] + be[1];
    r[2] = (x[2] - mu) * rstd * gm[2] + be[2];
    r[3] = (x[3] - mu) * rstd * gm[3] + be[3];
    ((f32x4*)px)[tid] = r;
}

// ---------------------------------------------------------------------------
extern "C" void kernel_launch(void* const* d_in, const int* in_sizes, int n_in,
                              void* d_out, int out_size, void* d_ws, size_t ws_size,
                              hipStream_t stream)
{
    const float* query = (const float*)d_in[0];
    const float* key   = (const float*)d_in[1];
    const float* value = (const float*)d_in[2];
    const float* Wq = (const float*)d_in[3];
    const float* bq = (const float*)d_in[4];
    const float* Wk = (const float*)d_in[5];
    const float* bk = (const float*)d_in[6];
    const float* Wv = (const float*)d_in[7];
    const float* bv = (const float*)d_in[8];
    const float* Wo = (const float*)d_in[9];
    const float* bo = (const float*)d_in[10];
    const float* gamma = (const float*)d_in[11];
    const float* beta  = (const float*)d_in[12];
    float* out = (float*)d_out;

    const size_t NTOK = (size_t)BATCH * SEQ;            // 8192
    const size_t ACT  = NTOK * MD;                      // 8M elems

    unsigned short* qa  = (unsigned short*)d_ws;        // bf16 query act
    unsigned short* ka  = qa + ACT;                     // bf16 key act; later ao
    unsigned short* va  = ka + ACT;                     // bf16 value act
    unsigned short* WqT = va + ACT;
    unsigned short* WkT = WqT + (size_t)MD * MD;
    unsigned short* WvT = WkT + (size_t)MD * MD;
    unsigned short* WoT = WvT + (size_t)MD * MD;
    unsigned short* qp  = WoT + (size_t)MD * MD;        // Q proj (pre-scaled)
    unsigned short* kp  = qp + ACT;                     // K proj
    unsigned short* vtp = kp + ACT;                     // V proj transposed [bh*64+d][s]
    unsigned short* ao  = ka;   // reuse (ka dead after K-projection)

    dim3 blk(256);

    prep_kernel<<<dim3(4096, 4), blk, 0, stream>>>(
        query, key, value, qa, ka, va, (int)ACT,
        Wq, Wk, Wv, Wo, WqT, WkT, WvT, WoT);

    dim3 gg(MD / 128, NTOK / 128, 3);   // (8, 64, 3)
    gemm_qkv<<<gg, blk, 0, stream>>>(qa, ka, va, WqT, WkT, WvT,
                                     bq, bk, bv, qp, kp, vtp);

    attn_mfma<<<dim3(SEQ / 256, 64), blk, 0, stream>>>(qp, kp, vtp, ao);

    gemm_o<<<dim3(MD / 128, NTOK / 128), blk, 0, stream>>>(ao, WoT, bo, query, out);

    ln_kernel<<<NTOK, blk, 0, stream>>>(out, gamma, beta);
}

// Round 8
// 223.641 us; speedup vs baseline: 2.3349x; 2.3349x over previous
//
#include <hip/hip_runtime.h>
#include <math.h>

#define MD 1024
#define NH 16
#define HD 64
#define BATCH 4
#define SEQ 2048

typedef __attribute__((ext_vector_type(8))) short short8;
typedef __attribute__((ext_vector_type(4))) short short4v;
typedef __attribute__((ext_vector_type(4))) float f32x4;
typedef __attribute__((ext_vector_type(2))) unsigned int uint2v;

#define GLOAD16(gp, lp) __builtin_amdgcn_global_load_lds( \
    (const __attribute__((address_space(1))) void*)(gp),  \
    (__attribute__((address_space(3))) void*)(lp), 16, 0, 0)

__device__ inline unsigned short f2b(float f) {
    unsigned u = __builtin_bit_cast(unsigned, f);
    unsigned r = (u + 0x7fffu + ((u >> 16) & 1u)) >> 16;
    return (unsigned short)r;
}
__device__ inline float b2f(unsigned short s) {
    return __builtin_bit_cast(float, ((unsigned)s) << 16);
}

// ---------------------------------------------------------------------------
// Fused prep: y<3 -> fp32->bf16 convert of q/k/v activations;
//             y==3 -> W[K][N] fp32 -> WT[N][K] bf16 for all 4 weights.
// Grid (4096, 4).  [proven R4/R5]
// ---------------------------------------------------------------------------
__global__ __launch_bounds__(256)
void prep_kernel(const float* __restrict__ x0, const float* __restrict__ x1,
                 const float* __restrict__ x2, unsigned short* __restrict__ y0,
                 unsigned short* __restrict__ y1, unsigned short* __restrict__ y2,
                 int n,
                 const float* __restrict__ W0, const float* __restrict__ W1,
                 const float* __restrict__ W2, const float* __restrict__ W3,
                 unsigned short* __restrict__ T0, unsigned short* __restrict__ T1,
                 unsigned short* __restrict__ T2, unsigned short* __restrict__ T3)
{
    __shared__ __attribute__((aligned(16))) float T[64][68];
    const int tid = threadIdx.x;
    if (blockIdx.y < 3) {
        const float* x = (blockIdx.y == 0) ? x0 : (blockIdx.y == 1) ? x1 : x2;
        unsigned short* y = (blockIdx.y == 0) ? y0 : (blockIdx.y == 1) ? y1 : y2;
        int i = (blockIdx.x * 256 + tid) * 8;
        if (i >= n) return;
        f32x4 a = *(const f32x4*)(x + i);
        f32x4 b = *(const f32x4*)(x + i + 4);
        short8 o;
        o[0] = (short)f2b(a[0]); o[1] = (short)f2b(a[1]);
        o[2] = (short)f2b(a[2]); o[3] = (short)f2b(a[3]);
        o[4] = (short)f2b(b[0]); o[5] = (short)f2b(b[1]);
        o[6] = (short)f2b(b[2]); o[7] = (short)f2b(b[3]);
        *(short8*)(y + i) = o;
        return;
    }
    const int bx = blockIdx.x;
    if (bx >= 1024) return;
    const int z = bx >> 8, t = bx & 255;
    const int nt = t & 15, kt = t >> 4;
    const float* W = (z == 0) ? W0 : (z == 1) ? W1 : (z == 2) ? W2 : W3;
    unsigned short* WT = (z == 0) ? T0 : (z == 1) ? T1 : (z == 2) ? T2 : T3;
    #pragma unroll
    for (int i = 0; i < 4; ++i) {
        int u = tid + i * 256;
        int row = u >> 4, c4 = u & 15;
        f32x4 v = *(const f32x4*)(W + (size_t)(kt * 64 + row) * MD + nt * 64 + c4 * 4);
        *(f32x4*)&T[row][c4 * 4] = v;
    }
    __syncthreads();
    #pragma unroll
    for (int i = 0; i < 2; ++i) {
        int u = tid + i * 256;
        int nn = u >> 3, c16 = u & 7;
        short8 o;
        #pragma unroll
        for (int j = 0; j < 8; ++j) o[j] = (short)f2b(T[c16 * 8 + j][nn]);
        *(short8*)(WT + (size_t)(nt * 64 + nn) * MD + kt * 64 + c16 * 8) = o;
    }
}

// ---------------------------------------------------------------------------
// GEMM core: 128x128 tile, BK=64, bf16 A/B via global_load_lds width-16,
// XCD-swizzled block id. [proven R3-R5]
// ---------------------------------------------------------------------------
__device__ __forceinline__
void gemm_core(const unsigned short* __restrict__ A,
               const unsigned short* __restrict__ Bt,
               short* As, short* Bs, f32x4 acc[4][4],
               int* obrow, int* obcol)
{
    const int tid = threadIdx.x;
    const int lane = tid & 63;
    const int wave = tid >> 6;
    const int wm = wave >> 1, wn = wave & 1;
    const int l15 = lane & 15, g = lane >> 4;

    const int nbx = gridDim.x;
    const int bid = blockIdx.y * nbx + blockIdx.x;
    const int cpx = (nbx * gridDim.y) >> 3;
    const int swz = (bid & 7) * cpx + (bid >> 3);
    const int brow = (swz / nbx) * 128;
    const int bcol = (swz % nbx) * 128;
    *obrow = brow; *obcol = bcol;

    #pragma unroll
    for (int m = 0; m < 4; ++m)
        #pragma unroll
        for (int n = 0; n < 4; ++n) acc[m][n] = (f32x4){0.f, 0.f, 0.f, 0.f};

    for (int k0 = 0; k0 < MD; k0 += 64) {
        __syncthreads();
        #pragma unroll
        for (int i = 0; i < 4; ++i) {
            const int U = (i * 4 + wave) * 64 + lane;
            const int row = U >> 3, c16 = U & 7;
            GLOAD16(A  + (size_t)(brow + row) * MD + k0 + c16 * 8, &As[U * 8]);
            GLOAD16(Bt + (size_t)(bcol + row) * MD + k0 + c16 * 8, &Bs[U * 8]);
        }
        __syncthreads();
        #pragma unroll
        for (int kk = 0; kk < 64; kk += 32) {
            short8 af[4], bf_[4];
            #pragma unroll
            for (int m = 0; m < 4; ++m)
                af[m] = *(const short8*)&As[(wm * 64 + m * 16 + l15) * 64 + kk + g * 8];
            #pragma unroll
            for (int n = 0; n < 4; ++n)
                bf_[n] = *(const short8*)&Bs[(wn * 64 + n * 16 + l15) * 64 + kk + g * 8];
            #pragma unroll
            for (int m = 0; m < 4; ++m)
                #pragma unroll
                for (int n = 0; n < 4; ++n)
                    acc[m][n] = __builtin_amdgcn_mfma_f32_16x16x32_bf16(af[m], bf_[n], acc[m][n], 0, 0, 0);
        }
    }
}

// Q/K/V projections in one launch; blockIdx.z selects.
// z=0: Q -> bf16 scaled by 0.125*log2(e).  z=1: K -> bf16.
// z=2: V -> transposed bf16 vt[bh*64+d][s].  [proven R5]
__global__ __launch_bounds__(256, 2)
void gemm_qkv(const unsigned short* __restrict__ A0, const unsigned short* __restrict__ A1,
              const unsigned short* __restrict__ A2,
              const unsigned short* __restrict__ B0, const unsigned short* __restrict__ B1,
              const unsigned short* __restrict__ B2,
              const float* __restrict__ b0, const float* __restrict__ b1,
              const float* __restrict__ b2,
              unsigned short* __restrict__ Cq, unsigned short* __restrict__ Ck,
              unsigned short* __restrict__ Cvt)
{
    __shared__ __attribute__((aligned(16))) short As[128 * 64];
    __shared__ __attribute__((aligned(16))) short Bs[128 * 64];
    const int z = blockIdx.z;
    const unsigned short* A  = (z == 0) ? A0 : (z == 1) ? A1 : A2;
    const unsigned short* Bt = (z == 0) ? B0 : (z == 1) ? B1 : B2;
    const float* bias        = (z == 0) ? b0 : (z == 1) ? b1 : b2;

    f32x4 acc[4][4];
    int brow, bcol;
    gemm_core(A, Bt, As, Bs, acc, &brow, &bcol);

    const int tid = threadIdx.x;
    const int lane = tid & 63;
    const int wave = tid >> 6;
    const int wm = wave >> 1, wn = wave & 1;
    const int l15 = lane & 15, g = lane >> 4;

    if (z == 2) {
        #pragma unroll
        for (int m = 0; m < 4; ++m) {
            #pragma unroll
            for (int n = 0; n < 4; ++n) {
                const int col = bcol + wn * 64 + n * 16 + l15;
                const int h = col >> 6, d = col & 63;
                const float bv_ = bias[col];
                const int row0 = brow + wm * 64 + m * 16 + 4 * g;
                const int bb = row0 >> 11, s = row0 & 2047;
                short4v pk;
                #pragma unroll
                for (int r = 0; r < 4; ++r) pk[r] = (short)f2b(acc[m][n][r] + bv_);
                *(short4v*)(Cvt + ((size_t)((bb << 4) + h) * 64 + d) * SEQ + s) = pk;
            }
        }
        return;
    }
    const float scale = (z == 0) ? (0.125f * 1.44269504088896f) : 1.0f;
    unsigned short* C = (z == 0) ? Cq : Ck;
    #pragma unroll
    for (int m = 0; m < 4; ++m) {
        #pragma unroll
        for (int n = 0; n < 4; ++n) {
            const int col = bcol + wn * 64 + n * 16 + l15;
            const float bcol_v = bias[col];
            #pragma unroll
            for (int r = 0; r < 4; ++r) {
                const size_t row = (size_t)(brow + wm * 64 + m * 16 + 4 * g + r);
                C[row * MD + col] = f2b((acc[m][n][r] + bcol_v) * scale);
            }
        }
    }
}

// O-projection: fp32 out + bias + residual. [proven R5]
__global__ __launch_bounds__(256, 2)
void gemm_o(const unsigned short* __restrict__ A, const unsigned short* __restrict__ Bt,
            const float* __restrict__ bias, const float* __restrict__ residual,
            float* __restrict__ Cf)
{
    __shared__ __attribute__((aligned(16))) short As[128 * 64];
    __shared__ __attribute__((aligned(16))) short Bs[128 * 64];
    f32x4 acc[4][4];
    int brow, bcol;
    gemm_core(A, Bt, As, Bs, acc, &brow, &bcol);

    const int tid = threadIdx.x;
    const int lane = tid & 63;
    const int wave = tid >> 6;
    const int wm = wave >> 1, wn = wave & 1;
    const int l15 = lane & 15, g = lane >> 4;
    #pragma unroll
    for (int m = 0; m < 4; ++m) {
        #pragma unroll
        for (int n = 0; n < 4; ++n) {
            const int col = bcol + wn * 64 + n * 16 + l15;
            const float bcol_v = bias[col];
            #pragma unroll
            for (int r = 0; r < 4; ++r) {
                const size_t row = (size_t)(brow + wm * 64 + m * 16 + 4 * g + r);
                Cf[row * MD + col] = acc[m][n][r] + bcol_v + residual[row * MD + col];
            }
        }
    }
}

// ---------------------------------------------------------------------------
// Flash attention, bf16 MFMA — EXACT R5 structure (measured 98 us):
// QBLK=256 (64 q-rows/wave), KV tile 64, double-buffered K/V LDS, ONE
// barrier/tile, 64KB LDS, (256,2). Only deltas vs R5: bh-grouped XCD swizzle
// (each XCD gets 8 full (b,h) = 4MB K/V = L2-sized) and fmax-chain pmax.
// Grid (8, 64), 256 thr = 4 waves.
// ---------------------------------------------------------------------------
__global__ __launch_bounds__(256, 2)
void attn_mfma(const unsigned short* __restrict__ qp,
               const unsigned short* __restrict__ kp,
               const unsigned short* __restrict__ vt,
               unsigned short* __restrict__ ao)
{
    __shared__ __attribute__((aligned(16))) short Ps[256 * 64];    // 32KB
    __shared__ __attribute__((aligned(16))) short Ks[2][64 * 64];  // 16KB
    __shared__ __attribute__((aligned(16))) short Vts[2][64 * 64]; // 16KB

    const int tid = threadIdx.x;
    const int lane = tid & 63;
    const int wave = tid >> 6;
    const int l15 = lane & 15, g = lane >> 4;

    // bh-grouped XCD swizzle: lin%8 fixes the XCD slot; all 8 q-tiles of a
    // bh (and 8 bh total) land on one XCD -> K/V working set = 4MB = L2.
    const int lin = blockIdx.y * gridDim.x + blockIdx.x;   // 0..511
    const int xi = lin & 7, j = lin >> 3;
    const int bh = xi + 8 * (j & 7);
    const int qt = j >> 3;

    const int b = bh >> 4, h = bh & 15;
    const size_t rowbase = (size_t)b * SEQ;
    const int q0 = qt * 256;
    const int wq = wave * 64;
    const int NT = SEQ / 64;

    // staging geometry
    const int r0 = tid >> 3, c16 = tid & 7;
    const int r1 = r0 + 32;
    const int lds0 = (r0 * 8 + (c16 ^ (r0 & 7))) * 8;
    const int lds1 = (r1 * 8 + (c16 ^ (r1 & 7))) * 8;
    const unsigned short* kbase = kp + (rowbase + r0) * MD + h * 64 + c16 * 8;
    const unsigned short* vbase = vt + ((size_t)bh * 64 + r0) * SEQ + c16 * 8;

    // ---- Q direct to registers (pre-scaled by Q-GEMM epilogue) ----
    short8 qreg[4][2];
    #pragma unroll
    for (int nf = 0; nf < 4; ++nf)
        #pragma unroll
        for (int ki = 0; ki < 2; ++ki)
            qreg[nf][ki] = *(const short8*)(qp + (rowbase + q0 + wq + nf * 16 + l15) * MD
                                               + h * 64 + ki * 32 + g * 8);

    // ---- stage KV tile 0 into buf 0 ----
    {
        short8 k0v = *(const short8*)(kbase);
        short8 k1v = *(const short8*)(kbase + 32 * MD);
        short8 v0v = *(const short8*)(vbase);
        short8 v1v = *(const short8*)(vbase + 32 * SEQ);
        *(short8*)&Ks[0][lds0]  = k0v;
        *(short8*)&Ks[0][lds1]  = k1v;
        *(short8*)&Vts[0][lds0] = v0v;
        *(short8*)&Vts[0][lds1] = v1v;
    }
    __syncthreads();

    short8 ones;
    #pragma unroll
    for (int jj = 0; jj < 8; ++jj) ones[jj] = (short)0x3F80;

    float mrun[4] = {-INFINITY, -INFINITY, -INFINITY, -INFINITY};
    f32x4 lrun[4];
    f32x4 off[4][4];
    #pragma unroll
    for (int qf = 0; qf < 4; ++qf) {
        lrun[qf] = (f32x4){0.f, 0.f, 0.f, 0.f};
        #pragma unroll
        for (int df = 0; df < 4; ++df) off[qf][df] = (f32x4){0.f, 0.f, 0.f, 0.f};
    }

    for (int kt = 0; kt < NT; ++kt) {
        const int cur = kt & 1;

        // prefetch next tile into regs (latency hides under QK+softmax+PV)
        short8 kreg0, kreg1, vreg0, vreg1;
        if (kt + 1 < NT) {
            const unsigned short* kb = kbase + (size_t)(kt + 1) * 64 * MD;
            const unsigned short* vb = vbase + (kt + 1) * 64;
            kreg0 = *(const short8*)(kb);
            kreg1 = *(const short8*)(kb + 32 * MD);
            vreg0 = *(const short8*)(vb);
            vreg1 = *(const short8*)(vb + 32 * SEQ);
        }

        // ---- S^T = K @ Q^T ----
        f32x4 sc[4][4];
        #pragma unroll
        for (int mf = 0; mf < 4; ++mf)
            #pragma unroll
            for (int nf = 0; nf < 4; ++nf) sc[mf][nf] = (f32x4){0.f, 0.f, 0.f, 0.f};
        __builtin_amdgcn_s_setprio(1);
        #pragma unroll
        for (int ki = 0; ki < 2; ++ki) {
            const int cu = ki * 4 + g;
            short8 af[4];
            #pragma unroll
            for (int mf = 0; mf < 4; ++mf) {
                int row = mf * 16 + l15;
                af[mf] = *(const short8*)&Ks[cur][(row * 8 + (cu ^ (row & 7))) * 8];
            }
            #pragma unroll
            for (int mf = 0; mf < 4; ++mf)
                #pragma unroll
                for (int nf = 0; nf < 4; ++nf)
                    sc[mf][nf] = __builtin_amdgcn_mfma_f32_16x16x32_bf16(af[mf], qreg[nf][ki], sc[mf][nf], 0, 0, 0);
        }
        __builtin_amdgcn_s_setprio(0);

        // ---- online softmax (log2 domain), defer-max THR=8 ----
        float pmax[4];
        #pragma unroll
        for (int nf = 0; nf < 4; ++nf) {
            float pm = fmaxf(fmaxf(sc[0][nf][0], sc[0][nf][1]), sc[0][nf][2]);
            pm = fmaxf(fmaxf(pm, sc[0][nf][3]), sc[1][nf][0]);
            pm = fmaxf(fmaxf(pm, sc[1][nf][1]), sc[1][nf][2]);
            pm = fmaxf(fmaxf(pm, sc[1][nf][3]), sc[2][nf][0]);
            pm = fmaxf(fmaxf(pm, sc[2][nf][1]), sc[2][nf][2]);
            pm = fmaxf(fmaxf(pm, sc[2][nf][3]), sc[3][nf][0]);
            pm = fmaxf(fmaxf(pm, sc[3][nf][1]), sc[3][nf][2]);
            pm = fmaxf(pm, sc[3][nf][3]);
            pm = fmaxf(pm, __shfl_xor(pm, 16));
            pm = fmaxf(pm, __shfl_xor(pm, 32));
            pmax[nf] = pm;
        }
        const int defer = (pmax[0] <= mrun[0] + 8.0f) && (pmax[1] <= mrun[1] + 8.0f) &&
                          (pmax[2] <= mrun[2] + 8.0f) && (pmax[3] <= mrun[3] + 8.0f);
        if (!__all(defer)) {
            float corr[4];
            #pragma unroll
            for (int nf = 0; nf < 4; ++nf) {
                float mnew = fmaxf(mrun[nf], pmax[nf]);
                corr[nf] = __builtin_amdgcn_exp2f(mrun[nf] - mnew);
                mrun[nf] = mnew;
            }
            #pragma unroll
            for (int qf = 0; qf < 4; ++qf)
                #pragma unroll
                for (int r = 0; r < 4; ++r) {
                    float c = __shfl(corr[qf], 4 * g + r);
                    lrun[qf][r] *= c;
                    #pragma unroll
                    for (int df = 0; df < 4; ++df) off[qf][df][r] *= c;
                }
        }
        #pragma unroll
        for (int nf = 0; nf < 4; ++nf) {
            const float nm = mrun[nf];
            #pragma unroll
            for (int mf = 0; mf < 4; ++mf)
                #pragma unroll
                for (int r = 0; r < 4; ++r)
                    sc[mf][nf][r] = __builtin_amdgcn_exp2f(sc[mf][nf][r] - nm);
        }

        // ---- pack P -> bf16, wave-own rows of Ps ----
        #pragma unroll
        for (int nf = 0; nf < 4; ++nf) {
            int row = wq + nf * 16 + l15;
            #pragma unroll
            for (int mf = 0; mf < 4; ++mf) {
                unsigned p01, p23;
                asm("v_cvt_pk_bf16_f32 %0, %1, %2" : "=v"(p01) : "v"(sc[mf][nf][0]), "v"(sc[mf][nf][1]));
                asm("v_cvt_pk_bf16_f32 %0, %1, %2" : "=v"(p23) : "v"(sc[mf][nf][2]), "v"(sc[mf][nf][3]));
                uint2v pk = {p01, p23};
                int su = (mf * 2 + (g >> 1)) ^ (row & 7);
                *(uint2v*)&Ps[row * 64 + su * 8 + (g & 1) * 4] = pk;
            }
        }

        // ---- PV + row-sum MFMA ----
        f32x4 ts[4];
        #pragma unroll
        for (int qf = 0; qf < 4; ++qf) ts[qf] = (f32x4){0.f, 0.f, 0.f, 0.f};
        __builtin_amdgcn_s_setprio(1);
        #pragma unroll
        for (int ki = 0; ki < 2; ++ki) {
            const int cu = ki * 4 + g;
            short8 pa[4], vb[4];
            #pragma unroll
            for (int qf = 0; qf < 4; ++qf) {
                int row = wq + qf * 16 + l15;
                pa[qf] = *(const short8*)&Ps[(row * 8 + (cu ^ (row & 7))) * 8];
            }
            #pragma unroll
            for (int df = 0; df < 4; ++df) {
                int d = df * 16 + l15;
                vb[df] = *(const short8*)&Vts[cur][(d * 8 + (cu ^ (d & 7))) * 8];
            }
            #pragma unroll
            for (int qf = 0; qf < 4; ++qf)
                #pragma unroll
                for (int df = 0; df < 4; ++df)
                    off[qf][df] = __builtin_amdgcn_mfma_f32_16x16x32_bf16(pa[qf], vb[df], off[qf][df], 0, 0, 0);
            #pragma unroll
            for (int qf = 0; qf < 4; ++qf)
                ts[qf] = __builtin_amdgcn_mfma_f32_16x16x32_bf16(pa[qf], ones, ts[qf], 0, 0, 0);
        }
        __builtin_amdgcn_s_setprio(0);
        #pragma unroll
        for (int qf = 0; qf < 4; ++qf)
            #pragma unroll
            for (int r = 0; r < 4; ++r) lrun[qf][r] += ts[qf][r];

        // ---- write next tile to buf[cur^1], then the one barrier ----
        if (kt + 1 < NT) {
            const int nxt = cur ^ 1;
            *(short8*)&Ks[nxt][lds0]  = kreg0;
            *(short8*)&Ks[nxt][lds1]  = kreg1;
            *(short8*)&Vts[nxt][lds0] = vreg0;
            *(short8*)&Vts[nxt][lds1] = vreg1;
        }
        __syncthreads();
    }

    // ---- normalize + store bf16 ----
    #pragma unroll
    for (int qf = 0; qf < 4; ++qf) {
        #pragma unroll
        for (int r = 0; r < 4; ++r) {
            const float inv = 1.0f / lrun[qf][r];
            const size_t row = rowbase + q0 + wq + qf * 16 + 4 * g + r;
            #pragma unroll
            for (int df = 0; df < 4; ++df) {
                float val = off[qf][df][r] * inv;
                ao[row * MD + h * 64 + df * 16 + l15] = f2b(val);
            }
        }
    }
}

// ---------------------------------------------------------------------------
// In-place LayerNorm over last dim (1024). One block per row, 256 threads.
// ---------------------------------------------------------------------------
__global__ __launch_bounds__(256)
void ln_kernel(float* __restrict__ X, const float* __restrict__ gamma,
               const float* __restrict__ beta)
{
    const int row = blockIdx.x;
    const int tid = threadIdx.x;
    float* px = X + (size_t)row * MD;
    f32x4 x = ((const f32x4*)px)[tid];
    float s  = x[0] + x[1] + x[2] + x[3];
    float ss = fmaf(x[0], x[0], fmaf(x[1], x[1], fmaf(x[2], x[2], x[3] * x[3])));
    #pragma unroll
    for (int off = 1; off < 64; off <<= 1) {
        s  += __shfl_xor(s,  off);
        ss += __shfl_xor(ss, off);
    }
    __shared__ float red[8];
    const int wid = tid >> 6;
    if ((tid & 63) == 0) { red[wid] = s; red[wid + 4] = ss; }
    __syncthreads();
    s  = red[0] + red[1] + red[2] + red[3];
    ss = red[4] + red[5] + red[6] + red[7];
    const float mu   = s * (1.0f / MD);
    const float var  = ss * (1.0f / MD) - mu * mu;
    const float rstd = rsqrtf(var + 1e-5f);
    f32x4 gm = ((const f32x4*)gamma)[tid];
    f32x4 be = ((const f32x4*)beta)[tid];
    f32x4 r;
    r[0] = (x[0] - mu) * rstd * gm[0] + be[0];
    r[1] = (x[1] - mu) * rstd * gm[1] + be[1];
    r[2] = (x[2] - mu) * rstd * gm[2] + be[2];
    r[3] = (x[3] - mu) * rstd * gm[3] + be[3];
    ((f32x4*)px)[tid] = r;
}

// ---------------------------------------------------------------------------
extern "C" void kernel_launch(void* const* d_in, const int* in_sizes, int n_in,
                              void* d_out, int out_size, void* d_ws, size_t ws_size,
                              hipStream_t stream)
{
    const float* query = (const float*)d_in[0];
    const float* key   = (const float*)d_in[1];
    const float* value = (const float*)d_in[2];
    const float* Wq = (const float*)d_in[3];
    const float* bq = (const float*)d_in[4];
    const float* Wk = (const float*)d_in[5];
    const float* bk = (const float*)d_in[6];
    const float* Wv = (const float*)d_in[7];
    const float* bv = (const float*)d_in[8];
    const float* Wo = (const float*)d_in[9];
    const float* bo = (const float*)d_in[10];
    const float* gamma = (const float*)d_in[11];
    const float* beta  = (const float*)d_in[12];
    float* out = (float*)d_out;

    const size_t NTOK = (size_t)BATCH * SEQ;            // 8192
    const size_t ACT  = NTOK * MD;                      // 8M elems

    unsigned short* qa  = (unsigned short*)d_ws;        // bf16 query act
    unsigned short* ka  = qa + ACT;                     // bf16 key act; later ao
    unsigned short* va  = ka + ACT;                     // bf16 value act
    unsigned short* WqT = va + ACT;
    unsigned short* WkT = WqT + (size_t)MD * MD;
    unsigned short* WvT = WkT + (size_t)MD * MD;
    unsigned short* WoT = WvT + (size_t)MD * MD;
    unsigned short* qp  = WoT + (size_t)MD * MD;        // Q proj (pre-scaled)
    unsigned short* kp  = qp + ACT;                     // K proj
    unsigned short* vtp = kp + ACT;                     // V proj transposed [bh*64+d][s]
    unsigned short* ao  = ka;   // reuse (ka dead after K-projection)

    dim3 blk(256);

    prep_kernel<<<dim3(4096, 4), blk, 0, stream>>>(
        query, key, value, qa, ka, va, (int)ACT,
        Wq, Wk, Wv, Wo, WqT, WkT, WvT, WoT);

    dim3 gg(MD / 128, NTOK / 128, 3);   // (8, 64, 3)
    gemm_qkv<<<gg, blk, 0, stream>>>(qa, ka, va, WqT, WkT, WvT,
                                     bq, bk, bv, qp, kp, vtp);

    attn_mfma<<<dim3(SEQ / 256, 64), blk, 0, stream>>>(qp, kp, vtp, ao);

    gemm_o<<<dim3(MD / 128, NTOK / 128), blk, 0, stream>>>(ao, WoT, bo, query, out);

    ln_kernel<<<NTOK, blk, 0, stream>>>(out, gamma, beta);
}

// Round 9
// 219.301 us; speedup vs baseline: 2.3812x; 1.0198x over previous
//
#include <hip/hip_runtime.h>
#include <math.h>

#define MD 1024
#define NH 16
#define HD 64
#define BATCH 4
#define SEQ 2048

typedef __attribute__((ext_vector_type(8))) short short8;
typedef __attribute__((ext_vector_type(4))) short short4v;
typedef __attribute__((ext_vector_type(4))) float f32x4;
typedef __attribute__((ext_vector_type(2))) unsigned int uint2v;

#define GLOAD16(gp, lp) __builtin_amdgcn_global_load_lds( \
    (const __attribute__((address_space(1))) void*)(gp),  \
    (__attribute__((address_space(3))) void*)(lp), 16, 0, 0)

__device__ inline unsigned short f2b(float f) {
    unsigned u = __builtin_bit_cast(unsigned, f);
    unsigned r = (u + 0x7fffu + ((u >> 16) & 1u)) >> 16;
    return (unsigned short)r;
}
__device__ inline float b2f(unsigned short s) {
    return __builtin_bit_cast(float, ((unsigned)s) << 16);
}

// ---------------------------------------------------------------------------
// Fused prep: y<3 -> fp32->bf16 convert of q/k/v activations;
//             y==3 -> W[K][N] fp32 -> WT[N][K] bf16 for all 4 weights.
// [proven R4-R8, unchanged]
// ---------------------------------------------------------------------------
__global__ __launch_bounds__(256)
void prep_kernel(const float* __restrict__ x0, const float* __restrict__ x1,
                 const float* __restrict__ x2, unsigned short* __restrict__ y0,
                 unsigned short* __restrict__ y1, unsigned short* __restrict__ y2,
                 int n,
                 const float* __restrict__ W0, const float* __restrict__ W1,
                 const float* __restrict__ W2, const float* __restrict__ W3,
                 unsigned short* __restrict__ T0, unsigned short* __restrict__ T1,
                 unsigned short* __restrict__ T2, unsigned short* __restrict__ T3)
{
    __shared__ __attribute__((aligned(16))) float T[64][68];
    const int tid = threadIdx.x;
    if (blockIdx.y < 3) {
        const float* x = (blockIdx.y == 0) ? x0 : (blockIdx.y == 1) ? x1 : x2;
        unsigned short* y = (blockIdx.y == 0) ? y0 : (blockIdx.y == 1) ? y1 : y2;
        int i = (blockIdx.x * 256 + tid) * 8;
        if (i >= n) return;
        f32x4 a = *(const f32x4*)(x + i);
        f32x4 b = *(const f32x4*)(x + i + 4);
        short8 o;
        o[0] = (short)f2b(a[0]); o[1] = (short)f2b(a[1]);
        o[2] = (short)f2b(a[2]); o[3] = (short)f2b(a[3]);
        o[4] = (short)f2b(b[0]); o[5] = (short)f2b(b[1]);
        o[6] = (short)f2b(b[2]); o[7] = (short)f2b(b[3]);
        *(short8*)(y + i) = o;
        return;
    }
    const int bx = blockIdx.x;
    if (bx >= 1024) return;
    const int z = bx >> 8, t = bx & 255;
    const int nt = t & 15, kt = t >> 4;
    const float* W = (z == 0) ? W0 : (z == 1) ? W1 : (z == 2) ? W2 : W3;
    unsigned short* WT = (z == 0) ? T0 : (z == 1) ? T1 : (z == 2) ? T2 : T3;
    #pragma unroll
    for (int i = 0; i < 4; ++i) {
        int u = tid + i * 256;
        int row = u >> 4, c4 = u & 15;
        f32x4 v = *(const f32x4*)(W + (size_t)(kt * 64 + row) * MD + nt * 64 + c4 * 4);
        *(f32x4*)&T[row][c4 * 4] = v;
    }
    __syncthreads();
    #pragma unroll
    for (int i = 0; i < 2; ++i) {
        int u = tid + i * 256;
        int nn = u >> 3, c16 = u & 7;
        short8 o;
        #pragma unroll
        for (int j = 0; j < 8; ++j) o[j] = (short)f2b(T[c16 * 8 + j][nn]);
        *(short8*)(WT + (size_t)(nt * 64 + nn) * MD + kt * 64 + c16 * 8) = o;
    }
}

// ---------------------------------------------------------------------------
// XCD-swizzled tile origin (nwg per z-slice = 512, %8==0).
// ---------------------------------------------------------------------------
__device__ __forceinline__ void tile_origin(int* obrow, int* obcol)
{
    const int nbx = gridDim.x;
    const int bid = blockIdx.y * nbx + blockIdx.x;
    const int cpx = (nbx * gridDim.y) >> 3;
    const int swz = (bid & 7) * cpx + (bid >> 3);
    *obrow = (swz / nbx) * 128;
    *obcol = (swz % nbx) * 128;
}

// ---------------------------------------------------------------------------
// GEMM core v3: 128x128 tile, BK=32, 3-buffer LDS rotation (48KB), counted
// s_waitcnt vmcnt(4) + raw s_barrier (ONE per K-step, no implicit drain).
// Tile t read from buf[t%3]; tile t+2 staged (global_load_lds w16) into
// buf[(t+2)%3] which has been idle since iter t-1 -> race-free with <=1
// barrier of wave skew. Last iter peeled with vmcnt(0).
// ---------------------------------------------------------------------------
__device__ __forceinline__
void gemm_core3(const unsigned short* __restrict__ A,
                const unsigned short* __restrict__ Bt,
                short* As, short* Bs, f32x4 acc[4][4],
                int brow, int bcol)
{
    const int tid = threadIdx.x;
    const int lane = tid & 63;
    const int wave = tid >> 6;
    const int wm = wave >> 1, wn = wave & 1;
    const int l15 = lane & 15, g = lane >> 4;

    #pragma unroll
    for (int m = 0; m < 4; ++m)
        #pragma unroll
        for (int n = 0; n < 4; ++n) acc[m][n] = (f32x4){0.f, 0.f, 0.f, 0.f};

    // staging geometry: tile = 128 rows x 32 k (bf16) = 512 x 16B units each
    // for A and B; 4 global_load_lds per thread per tile.
    const int rA = tid >> 2, cA = (tid & 3) * 8;     // unit tid
    const int rB = rA + 64;                          // unit tid+256

    auto stage = [&](int t) {
        const int kb = t << 5;
        short* as = As + (t % 3) * 4096;
        short* bs = Bs + (t % 3) * 4096;
        GLOAD16(A  + (size_t)(brow + rA) * MD + kb + cA, as + tid * 8);
        GLOAD16(A  + (size_t)(brow + rB) * MD + kb + cA, as + (tid + 256) * 8);
        GLOAD16(Bt + (size_t)(bcol + rA) * MD + kb + cA, bs + tid * 8);
        GLOAD16(Bt + (size_t)(bcol + rB) * MD + kb + cA, bs + (tid + 256) * 8);
    };

    stage(0);
    stage(1);

    for (int t = 0; t < 31; ++t) {
        // counted wait: drain oldest tile (4 loads), keep next tile in flight
        asm volatile("s_waitcnt vmcnt(4)" ::: "memory");
        __builtin_amdgcn_s_barrier();
        __builtin_amdgcn_sched_barrier(0);
        if (t < 30) stage(t + 2);
        const short* as = As + (t % 3) * 4096;
        const short* bs = Bs + (t % 3) * 4096;
        short8 af[4], bf_[4];
        #pragma unroll
        for (int m = 0; m < 4; ++m)
            af[m] = *(const short8*)&as[(wm * 64 + m * 16 + l15) * 32 + g * 8];
        #pragma unroll
        for (int n = 0; n < 4; ++n)
            bf_[n] = *(const short8*)&bs[(wn * 64 + n * 16 + l15) * 32 + g * 8];
        #pragma unroll
        for (int m = 0; m < 4; ++m)
            #pragma unroll
            for (int n = 0; n < 4; ++n)
                acc[m][n] = __builtin_amdgcn_mfma_f32_16x16x32_bf16(af[m], bf_[n], acc[m][n], 0, 0, 0);
    }
    // peeled last iter: nothing left in flight after this wait
    {
        asm volatile("s_waitcnt vmcnt(0)" ::: "memory");
        __builtin_amdgcn_s_barrier();
        __builtin_amdgcn_sched_barrier(0);
        const short* as = As + (31 % 3) * 4096;
        const short* bs = Bs + (31 % 3) * 4096;
        short8 af[4], bf_[4];
        #pragma unroll
        for (int m = 0; m < 4; ++m)
            af[m] = *(const short8*)&as[(wm * 64 + m * 16 + l15) * 32 + g * 8];
        #pragma unroll
        for (int n = 0; n < 4; ++n)
            bf_[n] = *(const short8*)&bs[(wn * 64 + n * 16 + l15) * 32 + g * 8];
        #pragma unroll
        for (int m = 0; m < 4; ++m)
            #pragma unroll
            for (int n = 0; n < 4; ++n)
                acc[m][n] = __builtin_amdgcn_mfma_f32_16x16x32_bf16(af[m], bf_[n], acc[m][n], 0, 0, 0);
    }
}

// Q/K/V projections in one launch; blockIdx.z selects.
// z=0: Q -> bf16 scaled by 0.125*log2(e).  z=1: K -> bf16.
// z=2: V -> transposed bf16 vt[bh*64+d][s].  [epilogues proven R5-R8]
__global__ __launch_bounds__(256, 2)
void gemm_qkv(const unsigned short* __restrict__ A0, const unsigned short* __restrict__ A1,
              const unsigned short* __restrict__ A2,
              const unsigned short* __restrict__ B0, const unsigned short* __restrict__ B1,
              const unsigned short* __restrict__ B2,
              const float* __restrict__ b0, const float* __restrict__ b1,
              const float* __restrict__ b2,
              unsigned short* __restrict__ Cq, unsigned short* __restrict__ Ck,
              unsigned short* __restrict__ Cvt)
{
    __shared__ __attribute__((aligned(16))) short As[3 * 4096];
    __shared__ __attribute__((aligned(16))) short Bs[3 * 4096];
    const int z = blockIdx.z;
    const unsigned short* A  = (z == 0) ? A0 : (z == 1) ? A1 : A2;
    const unsigned short* Bt = (z == 0) ? B0 : (z == 1) ? B1 : B2;
    const float* bias        = (z == 0) ? b0 : (z == 1) ? b1 : b2;

    int brow, bcol;
    tile_origin(&brow, &bcol);
    f32x4 acc[4][4];
    gemm_core3(A, Bt, As, Bs, acc, brow, bcol);

    const int tid = threadIdx.x;
    const int lane = tid & 63;
    const int wave = tid >> 6;
    const int wm = wave >> 1, wn = wave & 1;
    const int l15 = lane & 15, g = lane >> 4;

    if (z == 2) {
        #pragma unroll
        for (int m = 0; m < 4; ++m) {
            #pragma unroll
            for (int n = 0; n < 4; ++n) {
                const int col = bcol + wn * 64 + n * 16 + l15;
                const int h = col >> 6, d = col & 63;
                const float bv_ = bias[col];
                const int row0 = brow + wm * 64 + m * 16 + 4 * g;
                const int bb = row0 >> 11, s = row0 & 2047;
                short4v pk;
                #pragma unroll
                for (int r = 0; r < 4; ++r) pk[r] = (short)f2b(acc[m][n][r] + bv_);
                *(short4v*)(Cvt + ((size_t)((bb << 4) + h) * 64 + d) * SEQ + s) = pk;
            }
        }
        return;
    }
    const float scale = (z == 0) ? (0.125f * 1.44269504088896f) : 1.0f;
    unsigned short* C = (z == 0) ? Cq : Ck;
    #pragma unroll
    for (int m = 0; m < 4; ++m) {
        #pragma unroll
        for (int n = 0; n < 4; ++n) {
            const int col = bcol + wn * 64 + n * 16 + l15;
            const float bcol_v = bias[col];
            #pragma unroll
            for (int r = 0; r < 4; ++r) {
                const size_t row = (size_t)(brow + wm * 64 + m * 16 + 4 * g + r);
                C[row * MD + col] = f2b((acc[m][n][r] + bcol_v) * scale);
            }
        }
    }
}

// O-projection: fp32 out + bias + residual.
__global__ __launch_bounds__(256, 2)
void gemm_o(const unsigned short* __restrict__ A, const unsigned short* __restrict__ Bt,
            const float* __restrict__ bias, const float* __restrict__ residual,
            float* __restrict__ Cf)
{
    __shared__ __attribute__((aligned(16))) short As[3 * 4096];
    __shared__ __attribute__((aligned(16))) short Bs[3 * 4096];
    int brow, bcol;
    tile_origin(&brow, &bcol);
    f32x4 acc[4][4];
    gemm_core3(A, Bt, As, Bs, acc, brow, bcol);

    const int tid = threadIdx.x;
    const int lane = tid & 63;
    const int wave = tid >> 6;
    const int wm = wave >> 1, wn = wave & 1;
    const int l15 = lane & 15, g = lane >> 4;
    #pragma unroll
    for (int m = 0; m < 4; ++m) {
        #pragma unroll
        for (int n = 0; n < 4; ++n) {
            const int col = bcol + wn * 64 + n * 16 + l15;
            const float bcol_v = bias[col];
            #pragma unroll
            for (int r = 0; r < 4; ++r) {
                const size_t row = (size_t)(brow + wm * 64 + m * 16 + 4 * g + r);
                Cf[row * MD + col] = acc[m][n][r] + bcol_v + residual[row * MD + col];
            }
        }
    }
}

// ---------------------------------------------------------------------------
// Flash attention, bf16 MFMA — EXACT R8 (measured 98 us, FETCH 24.7MB).
// ---------------------------------------------------------------------------
__global__ __launch_bounds__(256, 2)
void attn_mfma(const unsigned short* __restrict__ qp,
               const unsigned short* __restrict__ kp,
               const unsigned short* __restrict__ vt,
               unsigned short* __restrict__ ao)
{
    __shared__ __attribute__((aligned(16))) short Ps[256 * 64];    // 32KB
    __shared__ __attribute__((aligned(16))) short Ks[2][64 * 64];  // 16KB
    __shared__ __attribute__((aligned(16))) short Vts[2][64 * 64]; // 16KB

    const int tid = threadIdx.x;
    const int lane = tid & 63;
    const int wave = tid >> 6;
    const int l15 = lane & 15, g = lane >> 4;

    const int lin = blockIdx.y * gridDim.x + blockIdx.x;   // 0..511
    const int xi = lin & 7, j = lin >> 3;
    const int bh = xi + 8 * (j & 7);
    const int qt = j >> 3;

    const int b = bh >> 4, h = bh & 15;
    const size_t rowbase = (size_t)b * SEQ;
    const int q0 = qt * 256;
    const int wq = wave * 64;
    const int NT = SEQ / 64;

    const int r0 = tid >> 3, c16 = tid & 7;
    const int r1 = r0 + 32;
    const int lds0 = (r0 * 8 + (c16 ^ (r0 & 7))) * 8;
    const int lds1 = (r1 * 8 + (c16 ^ (r1 & 7))) * 8;
    const unsigned short* kbase = kp + (rowbase + r0) * MD + h * 64 + c16 * 8;
    const unsigned short* vbase = vt + ((size_t)bh * 64 + r0) * SEQ + c16 * 8;

    short8 qreg[4][2];
    #pragma unroll
    for (int nf = 0; nf < 4; ++nf)
        #pragma unroll
        for (int ki = 0; ki < 2; ++ki)
            qreg[nf][ki] = *(const short8*)(qp + (rowbase + q0 + wq + nf * 16 + l15) * MD
                                               + h * 64 + ki * 32 + g * 8);

    {
        short8 k0v = *(const short8*)(kbase);
        short8 k1v = *(const short8*)(kbase + 32 * MD);
        short8 v0v = *(const short8*)(vbase);
        short8 v1v = *(const short8*)(vbase + 32 * SEQ);
        *(short8*)&Ks[0][lds0]  = k0v;
        *(short8*)&Ks[0][lds1]  = k1v;
        *(short8*)&Vts[0][lds0] = v0v;
        *(short8*)&Vts[0][lds1] = v1v;
    }
    __syncthreads();

    short8 ones;
    #pragma unroll
    for (int jj = 0; jj < 8; ++jj) ones[jj] = (short)0x3F80;

    float mrun[4] = {-INFINITY, -INFINITY, -INFINITY, -INFINITY};
    f32x4 lrun[4];
    f32x4 off[4][4];
    #pragma unroll
    for (int qf = 0; qf < 4; ++qf) {
        lrun[qf] = (f32x4){0.f, 0.f, 0.f, 0.f};
        #pragma unroll
        for (int df = 0; df < 4; ++df) off[qf][df] = (f32x4){0.f, 0.f, 0.f, 0.f};
    }

    for (int kt = 0; kt < NT; ++kt) {
        const int cur = kt & 1;

        short8 kreg0, kreg1, vreg0, vreg1;
        if (kt + 1 < NT) {
            const unsigned short* kb = kbase + (size_t)(kt + 1) * 64 * MD;
            const unsigned short* vb = vbase + (kt + 1) * 64;
            kreg0 = *(const short8*)(kb);
            kreg1 = *(const short8*)(kb + 32 * MD);
            vreg0 = *(const short8*)(vb);
            vreg1 = *(const short8*)(vb + 32 * SEQ);
        }

        f32x4 sc[4][4];
        #pragma unroll
        for (int mf = 0; mf < 4; ++mf)
            #pragma unroll
            for (int nf = 0; nf < 4; ++nf) sc[mf][nf] = (f32x4){0.f, 0.f, 0.f, 0.f};
        __builtin_amdgcn_s_setprio(1);
        #pragma unroll
        for (int ki = 0; ki < 2; ++ki) {
            const int cu = ki * 4 + g;
            short8 af[4];
            #pragma unroll
            for (int mf = 0; mf < 4; ++mf) {
                int row = mf * 16 + l15;
                af[mf] = *(const short8*)&Ks[cur][(row * 8 + (cu ^ (row & 7))) * 8];
            }
            #pragma unroll
            for (int mf = 0; mf < 4; ++mf)
                #pragma unroll
                for (int nf = 0; nf < 4; ++nf)
                    sc[mf][nf] = __builtin_amdgcn_mfma_f32_16x16x32_bf16(af[mf], qreg[nf][ki], sc[mf][nf], 0, 0, 0);
        }
        __builtin_amdgcn_s_setprio(0);

        float pmax[4];
        #pragma unroll
        for (int nf = 0; nf < 4; ++nf) {
            float pm = fmaxf(fmaxf(sc[0][nf][0], sc[0][nf][1]), sc[0][nf][2]);
            pm = fmaxf(fmaxf(pm, sc[0][nf][3]), sc[1][nf][0]);
            pm = fmaxf(fmaxf(pm, sc[1][nf][1]), sc[1][nf][2]);
            pm = fmaxf(fmaxf(pm, sc[1][nf][3]), sc[2][nf][0]);
            pm = fmaxf(fmaxf(pm, sc[2][nf][1]), sc[2][nf][2]);
            pm = fmaxf(fmaxf(pm, sc[2][nf][3]), sc[3][nf][0]);
            pm = fmaxf(fmaxf(pm, sc[3][nf][1]), sc[3][nf][2]);
            pm = fmaxf(pm, sc[3][nf][3]);
            pm = fmaxf(pm, __shfl_xor(pm, 16));
            pm = fmaxf(pm, __shfl_xor(pm, 32));
            pmax[nf] = pm;
        }
        const int defer = (pmax[0] <= mrun[0] + 8.0f) && (pmax[1] <= mrun[1] + 8.0f) &&
                          (pmax[2] <= mrun[2] + 8.0f) && (pmax[3] <= mrun[3] + 8.0f);
        if (!__all(defer)) {
            float corr[4];
            #pragma unroll
            for (int nf = 0; nf < 4; ++nf) {
                float mnew = fmaxf(mrun[nf], pmax[nf]);
                corr[nf] = __builtin_amdgcn_exp2f(mrun[nf] - mnew);
                mrun[nf] = mnew;
            }
            #pragma unroll
            for (int qf = 0; qf < 4; ++qf)
                #pragma unroll
                for (int r = 0; r < 4; ++r) {
                    float c = __shfl(corr[qf], 4 * g + r);
                    lrun[qf][r] *= c;
                    #pragma unroll
                    for (int df = 0; df < 4; ++df) off[qf][df][r] *= c;
                }
        }
        #pragma unroll
        for (int nf = 0; nf < 4; ++nf) {
            const float nm = mrun[nf];
            #pragma unroll
            for (int mf = 0; mf < 4; ++mf)
                #pragma unroll
                for (int r = 0; r < 4; ++r)
                    sc[mf][nf][r] = __builtin_amdgcn_exp2f(sc[mf][nf][r] - nm);
        }

        #pragma unroll
        for (int nf = 0; nf < 4; ++nf) {
            int row = wq + nf * 16 + l15;
            #pragma unroll
            for (int mf = 0; mf < 4; ++mf) {
                unsigned p01, p23;
                asm("v_cvt_pk_bf16_f32 %0, %1, %2" : "=v"(p01) : "v"(sc[mf][nf][0]), "v"(sc[mf][nf][1]));
                asm("v_cvt_pk_bf16_f32 %0, %1, %2" : "=v"(p23) : "v"(sc[mf][nf][2]), "v"(sc[mf][nf][3]));
                uint2v pk = {p01, p23};
                int su = (mf * 2 + (g >> 1)) ^ (row & 7);
                *(uint2v*)&Ps[row * 64 + su * 8 + (g & 1) * 4] = pk;
            }
        }

        f32x4 ts[4];
        #pragma unroll
        for (int qf = 0; qf < 4; ++qf) ts[qf] = (f32x4){0.f, 0.f, 0.f, 0.f};
        __builtin_amdgcn_s_setprio(1);
        #pragma unroll
        for (int ki = 0; ki < 2; ++ki) {
            const int cu = ki * 4 + g;
            short8 pa[4], vb[4];
            #pragma unroll
            for (int qf = 0; qf < 4; ++qf) {
                int row = wq + qf * 16 + l15;
                pa[qf] = *(const short8*)&Ps[(row * 8 + (cu ^ (row & 7))) * 8];
            }
            #pragma unroll
            for (int df = 0; df < 4; ++df) {
                int d = df * 16 + l15;
                vb[df] = *(const short8*)&Vts[cur][(d * 8 + (cu ^ (d & 7))) * 8];
            }
            #pragma unroll
            for (int qf = 0; qf < 4; ++qf)
                #pragma unroll
                for (int df = 0; df < 4; ++df)
                    off[qf][df] = __builtin_amdgcn_mfma_f32_16x16x32_bf16(pa[qf], vb[df], off[qf][df], 0, 0, 0);
            #pragma unroll
            for (int qf = 0; qf < 4; ++qf)
                ts[qf] = __builtin_amdgcn_mfma_f32_16x16x32_bf16(pa[qf], ones, ts[qf], 0, 0, 0);
        }
        __builtin_amdgcn_s_setprio(0);
        #pragma unroll
        for (int qf = 0; qf < 4; ++qf)
            #pragma unroll
            for (int r = 0; r < 4; ++r) lrun[qf][r] += ts[qf][r];

        if (kt + 1 < NT) {
            const int nxt = cur ^ 1;
            *(short8*)&Ks[nxt][lds0]  = kreg0;
            *(short8*)&Ks[nxt][lds1]  = kreg1;
            *(short8*)&Vts[nxt][lds0] = vreg0;
            *(short8*)&Vts[nxt][lds1] = vreg1;
        }
        __syncthreads();
    }

    #pragma unroll
    for (int qf = 0; qf < 4; ++qf) {
        #pragma unroll
        for (int r = 0; r < 4; ++r) {
            const float inv = 1.0f / lrun[qf][r];
            const size_t row = rowbase + q0 + wq + qf * 16 + 4 * g + r;
            #pragma unroll
            for (int df = 0; df < 4; ++df) {
                float val = off[qf][df][r] * inv;
                ao[row * MD + h * 64 + df * 16 + l15] = f2b(val);
            }
        }
    }
}

// ---------------------------------------------------------------------------
// In-place LayerNorm over last dim (1024). One block per row, 256 threads.
// ---------------------------------------------------------------------------
__global__ __launch_bounds__(256)
void ln_kernel(float* __restrict__ X, const float* __restrict__ gamma,
               const float* __restrict__ beta)
{
    const int row = blockIdx.x;
    const int tid = threadIdx.x;
    float* px = X + (size_t)row * MD;
    f32x4 x = ((const f32x4*)px)[tid];
    float s  = x[0] + x[1] + x[2] + x[3];
    float ss = fmaf(x[0], x[0], fmaf(x[1], x[1], fmaf(x[2], x[2], x[3] * x[3])));
    #pragma unroll
    for (int off = 1; off < 64; off <<= 1) {
        s  += __shfl_xor(s,  off);
        ss += __shfl_xor(ss, off);
    }
    __shared__ float red[8];
    const int wid = tid >> 6;
    if ((tid & 63) == 0) { red[wid] = s; red[wid + 4] = ss; }
    __syncthreads();
    s  = red[0] + red[1] + red[2] + red[3];
    ss = red[4] + red[5] + red[6] + red[7];
    const float mu   = s * (1.0f / MD);
    const float var  = ss * (1.0f / MD) - mu * mu;
    const float rstd = rsqrtf(var + 1e-5f);
    f32x4 gm = ((const f32x4*)gamma)[tid];
    f32x4 be = ((const f32x4*)beta)[tid];
    f32x4 r;
    r[0] = (x[0] - mu) * rstd * gm[0] + be[0];
    r[1] = (x[1] - mu) * rstd * gm[1] + be[1];
    r[2] = (x[2] - mu) * rstd * gm[2] + be[2];
    r[3] = (x[3] - mu) * rstd * gm[3] + be[3];
    ((f32x4*)px)[tid] = r;
}

// ---------------------------------------------------------------------------
extern "C" void kernel_launch(void* const* d_in, const int* in_sizes, int n_in,
                              void* d_out, int out_size, void* d_ws, size_t ws_size,
                              hipStream_t stream)
{
    const float* query = (const float*)d_in[0];
    const float* key   = (const float*)d_in[1];
    const float* value = (const float*)d_in[2];
    const float* Wq = (const float*)d_in[3];
    const float* bq = (const float*)d_in[4];
    const float* Wk = (const float*)d_in[5];
    const float* bk = (const float*)d_in[6];
    const float* Wv = (const float*)d_in[7];
    const float* bv = (const float*)d_in[8];
    const float* Wo = (const float*)d_in[9];
    const float* bo = (const float*)d_in[10];
    const float* gamma = (const float*)d_in[11];
    const float* beta  = (const float*)d_in[12];
    float* out = (float*)d_out;

    const size_t NTOK = (size_t)BATCH * SEQ;            // 8192
    const size_t ACT  = NTOK * MD;                      // 8M elems

    unsigned short* qa  = (unsigned short*)d_ws;        // bf16 query act
    unsigned short* ka  = qa + ACT;                     // bf16 key act; later ao
    unsigned short* va  = ka + ACT;                     // bf16 value act
    unsigned short* WqT = va + ACT;
    unsigned short* WkT = WqT + (size_t)MD * MD;
    unsigned short* WvT = WkT + (size_t)MD * MD;
    unsigned short* WoT = WvT + (size_t)MD * MD;
    unsigned short* qp  = WoT + (size_t)MD * MD;        // Q proj (pre-scaled)
    unsigned short* kp  = qp + ACT;                     // K proj
    unsigned short* vtp = kp + ACT;                     // V proj transposed [bh*64+d][s]
    unsigned short* ao  = ka;   // reuse (ka dead after K-projection)

    dim3 blk(256);

    prep_kernel<<<dim3(4096, 4), blk, 0, stream>>>(
        query, key, value, qa, ka, va, (int)ACT,
        Wq, Wk, Wv, Wo, WqT, WkT, WvT, WoT);

    dim3 gg(MD / 128, NTOK / 128, 3);   // (8, 64, 3)
    gemm_qkv<<<gg, blk, 0, stream>>>(qa, ka, va, WqT, WkT, WvT,
                                     bq, bk, bv, qp, kp, vtp);

    attn_mfma<<<dim3(SEQ / 256, 64), blk, 0, stream>>>(qp, kp, vtp, ao);

    gemm_o<<<dim3(MD / 128, NTOK / 128), blk, 0, stream>>>(ao, WoT, bo, query, out);

    ln_kernel<<<NTOK, blk, 0, stream>>>(out, gamma, beta);
}